// Round 1
// baseline (589.404 us; speedup 1.0000x reference)
//
#include <hip/hip_runtime.h>
#include <math.h>

#define B_   8
#define F_   4
#define S_   512
#define D_   256
#define H_   8
#define DK_  32
#define DV_  32
#define NBF  32                 // B*F
#define NROWS (NBF * S_)        // 16384
#define LN_EPS 1e-5f

// ---------------------------------------------------------------------------
// Kernel 1: q/k/v projections, fused.  C = X @ W  for 3 weight matrices.
// Block: 256 threads, TM=16 rows.  Thread j owns output column j.
// ---------------------------------------------------------------------------
__global__ __launch_bounds__(256) void qkv_kernel(
    const float* __restrict__ x,
    const float* __restrict__ Wq, const float* __restrict__ Wk,
    const float* __restrict__ Wv,
    float* __restrict__ qo, float* __restrict__ ko, float* __restrict__ vo)
{
    const int TM = 16;
    __shared__ float xs[TM][D_];
    const int r0 = blockIdx.x * TM;
    const int j  = threadIdx.x;

    for (int i = threadIdx.x; i < TM * D_ / 4; i += 256) {
        int r = i / (D_ / 4);
        int c = (i % (D_ / 4)) * 4;
        *(float4*)&xs[r][c] = *(const float4*)&x[(size_t)(r0 + r) * D_ + c];
    }
    __syncthreads();

    float aq[TM], ak[TM], av[TM];
#pragma unroll
    for (int r = 0; r < TM; ++r) { aq[r] = 0.f; ak[r] = 0.f; av[r] = 0.f; }

    for (int kk = 0; kk < D_; kk += 4) {
        float wq0 = Wq[(kk + 0) * D_ + j], wq1 = Wq[(kk + 1) * D_ + j];
        float wq2 = Wq[(kk + 2) * D_ + j], wq3 = Wq[(kk + 3) * D_ + j];
        float wk0 = Wk[(kk + 0) * D_ + j], wk1 = Wk[(kk + 1) * D_ + j];
        float wk2 = Wk[(kk + 2) * D_ + j], wk3 = Wk[(kk + 3) * D_ + j];
        float wv0 = Wv[(kk + 0) * D_ + j], wv1 = Wv[(kk + 1) * D_ + j];
        float wv2 = Wv[(kk + 2) * D_ + j], wv3 = Wv[(kk + 3) * D_ + j];
#pragma unroll
        for (int r = 0; r < TM; ++r) {
            float4 xv = *(const float4*)&xs[r][kk];
            aq[r] = fmaf(xv.x, wq0, aq[r]); aq[r] = fmaf(xv.y, wq1, aq[r]);
            aq[r] = fmaf(xv.z, wq2, aq[r]); aq[r] = fmaf(xv.w, wq3, aq[r]);
            ak[r] = fmaf(xv.x, wk0, ak[r]); ak[r] = fmaf(xv.y, wk1, ak[r]);
            ak[r] = fmaf(xv.z, wk2, ak[r]); ak[r] = fmaf(xv.w, wk3, ak[r]);
            av[r] = fmaf(xv.x, wv0, av[r]); av[r] = fmaf(xv.y, wv1, av[r]);
            av[r] = fmaf(xv.z, wv2, av[r]); av[r] = fmaf(xv.w, wv3, av[r]);
        }
    }
#pragma unroll
    for (int r = 0; r < TM; ++r) {
        qo[(size_t)(r0 + r) * D_ + j] = aq[r];
        ko[(size_t)(r0 + r) * D_ + j] = ak[r];
        vo[(size_t)(r0 + r) * D_ + j] = av[r];
    }
}

// ---------------------------------------------------------------------------
// Kernel 2: per (b,f,h): scores = qk^T/sqrt(32)+res (written to d_out),
// softmax over the QUERY axis s (per-column t), ctx = attn^T-weighted V.
// One 512-thread block per (b,f,h).
//   Phase A: thread t owns column t; online max/sum while writing scores.
//   Phase B: thread s owns ctx row s; re-reads scores row, accumulates V.
// ---------------------------------------------------------------------------
__global__ __launch_bounds__(512) void attn_kernel(
    const float* __restrict__ q, const float* __restrict__ k,
    const float* __restrict__ v, const float* __restrict__ res,
    float* __restrict__ sc_out, float* __restrict__ ctx)
{
    const int g  = blockIdx.x;        // bf*H + h
    const int bf = g >> 3;
    const int h  = g & 7;
    const size_t rowbase = (size_t)bf * S_ * D_ + (size_t)h * DK_;
    const size_t sbase   = (size_t)g * S_ * S_;
    const int t = threadIdx.x;

    // K row for column t into registers
    float kreg[DK_];
#pragma unroll
    for (int i = 0; i < DK_; i += 4) {
        float4 kv = *(const float4*)&k[rowbase + (size_t)t * D_ + i];
        kreg[i] = kv.x; kreg[i + 1] = kv.y; kreg[i + 2] = kv.z; kreg[i + 3] = kv.w;
    }

    const float scale = 0.17677669529663687f;  // 1/sqrt(32)
    float m = -1e30f, z = 0.f;
    for (int s = 0; s < S_; ++s) {
        float sc = 0.f;
#pragma unroll
        for (int i = 0; i < DK_; i += 4) {
            float4 qv = *(const float4*)&q[rowbase + (size_t)s * D_ + i];
            sc = fmaf(qv.x, kreg[i + 0], sc);
            sc = fmaf(qv.y, kreg[i + 1], sc);
            sc = fmaf(qv.z, kreg[i + 2], sc);
            sc = fmaf(qv.w, kreg[i + 3], sc);
        }
        sc = fmaf(sc, scale, res[sbase + (size_t)s * S_ + t]);
        sc_out[sbase + (size_t)s * S_ + t] = sc;
        float nm = fmaxf(m, sc);
        z = z * __expf(m - nm) + __expf(sc - nm);
        m = nm;
    }

    __shared__ float Ms[S_];
    __shared__ float iZs[S_];
    Ms[t]  = m;
    iZs[t] = 1.f / z;
    __threadfence_block();
    __syncthreads();

    // Phase B: thread = query row s
    const int srow = threadIdx.x;
    float acc[DV_];
#pragma unroll
    for (int i = 0; i < DV_; ++i) acc[i] = 0.f;
    const size_t vrow = (size_t)bf * S_ * D_ + (size_t)h * DV_;
    const float* scrow = &sc_out[sbase + (size_t)srow * S_];

    for (int tt = 0; tt < S_; tt += 4) {
        float4 s4 = *(const float4*)&scrow[tt];
        float e[4];
        e[0] = __expf(s4.x - Ms[tt + 0]) * iZs[tt + 0];
        e[1] = __expf(s4.y - Ms[tt + 1]) * iZs[tt + 1];
        e[2] = __expf(s4.z - Ms[tt + 2]) * iZs[tt + 2];
        e[3] = __expf(s4.w - Ms[tt + 3]) * iZs[tt + 3];
#pragma unroll
        for (int u = 0; u < 4; ++u) {
            const float* vr = &v[vrow + (size_t)(tt + u) * D_];
            float eu = e[u];
#pragma unroll
            for (int i = 0; i < DV_; i += 4) {
                float4 v4 = *(const float4*)&vr[i];
                acc[i + 0] = fmaf(eu, v4.x, acc[i + 0]);
                acc[i + 1] = fmaf(eu, v4.y, acc[i + 1]);
                acc[i + 2] = fmaf(eu, v4.z, acc[i + 2]);
                acc[i + 3] = fmaf(eu, v4.w, acc[i + 3]);
            }
        }
    }

    float* crow = &ctx[((size_t)bf * S_ + srow) * D_ + (size_t)h * DV_];
#pragma unroll
    for (int i = 0; i < DV_; i += 4) {
        float4 o;
        o.x = acc[i]; o.y = acc[i + 1]; o.z = acc[i + 2]; o.w = acc[i + 3];
        *(float4*)&crow[i] = o;
    }
}

// ---------------------------------------------------------------------------
// Kernel 3: out = LayerNorm(ctx @ W_fc + x) * g + b
// ---------------------------------------------------------------------------
__global__ __launch_bounds__(256) void out_kernel(
    const float* __restrict__ ctx, const float* __restrict__ x,
    const float* __restrict__ Wfc, const float* __restrict__ gam,
    const float* __restrict__ bet, float* __restrict__ out)
{
    const int TM = 16;
    __shared__ float cs[TM][D_];
    __shared__ float red[TM][4][2];
    const int r0 = blockIdx.x * TM;
    const int j  = threadIdx.x;

    for (int i = threadIdx.x; i < TM * D_ / 4; i += 256) {
        int r = i / (D_ / 4);
        int c = (i % (D_ / 4)) * 4;
        *(float4*)&cs[r][c] = *(const float4*)&ctx[(size_t)(r0 + r) * D_ + c];
    }
    __syncthreads();

    float y[TM];
#pragma unroll
    for (int r = 0; r < TM; ++r) y[r] = 0.f;

    for (int kk = 0; kk < D_; kk += 4) {
        float w0 = Wfc[(kk + 0) * D_ + j], w1 = Wfc[(kk + 1) * D_ + j];
        float w2 = Wfc[(kk + 2) * D_ + j], w3 = Wfc[(kk + 3) * D_ + j];
#pragma unroll
        for (int r = 0; r < TM; ++r) {
            float4 c4 = *(const float4*)&cs[r][kk];
            y[r] = fmaf(c4.x, w0, y[r]); y[r] = fmaf(c4.y, w1, y[r]);
            y[r] = fmaf(c4.z, w2, y[r]); y[r] = fmaf(c4.w, w3, y[r]);
        }
    }
#pragma unroll
    for (int r = 0; r < TM; ++r) y[r] += x[(size_t)(r0 + r) * D_ + j];

    const int lane = threadIdx.x & 63;
    const int w    = threadIdx.x >> 6;
#pragma unroll
    for (int r = 0; r < TM; ++r) {
        float s1 = y[r], s2 = y[r] * y[r];
        for (int off = 32; off; off >>= 1) {
            s1 += __shfl_xor(s1, off);
            s2 += __shfl_xor(s2, off);
        }
        if (lane == 0) { red[r][w][0] = s1; red[r][w][1] = s2; }
    }
    __syncthreads();

#pragma unroll
    for (int r = 0; r < TM; ++r) {
        float s1 = red[r][0][0] + red[r][1][0] + red[r][2][0] + red[r][3][0];
        float s2 = red[r][0][1] + red[r][1][1] + red[r][2][1] + red[r][3][1];
        float mu  = s1 * (1.f / D_);
        float var = s2 * (1.f / D_) - mu * mu;
        float o = (y[r] - mu) * rsqrtf(var + LN_EPS) * gam[j] + bet[j];
        out[(size_t)(r0 + r) * D_ + j] = o;
    }
}

extern "C" void kernel_launch(void* const* d_in, const int* in_sizes, int n_in,
                              void* d_out, int out_size, void* d_ws, size_t ws_size,
                              hipStream_t stream)
{
    const float* x   = (const float*)d_in[0];
    const float* res = (const float*)d_in[1];
    const float* Wq  = (const float*)d_in[2];
    const float* Wk  = (const float*)d_in[3];
    const float* Wv  = (const float*)d_in[4];
    const float* Wfc = (const float*)d_in[5];
    const float* gam = (const float*)d_in[6];
    const float* bet = (const float*)d_in[7];

    float* out    = (float*)d_out;
    float* scores = out + (size_t)NROWS * D_;   // output 1 starts after output 0

    float* q   = (float*)d_ws;
    float* k   = q + (size_t)NROWS * D_;
    float* v   = k + (size_t)NROWS * D_;
    float* ctx = v + (size_t)NROWS * D_;

    qkv_kernel<<<dim3(NROWS / 16), 256, 0, stream>>>(x, Wq, Wk, Wv, q, k, v);
    attn_kernel<<<dim3(NBF * H_), 512, 0, stream>>>(q, k, v, res, scores, ctx);
    out_kernel<<<dim3(NROWS / 16), 256, 0, stream>>>(ctx, x, Wfc, gam, bet, out);
}

// Round 2
// 438.995 us; speedup vs baseline: 1.3426x; 1.3426x over previous
//
#include <hip/hip_runtime.h>
#include <math.h>

#define B_   8
#define F_   4
#define S_   512
#define D_   256
#define H_   8
#define DK_  32
#define DV_  32
#define NBF  32                 // B*F
#define NROWS (NBF * S_)        // 16384
#define NG   (NBF * H_)         // 256 (b,f,h) groups
#define LN_EPS 1e-5f

// ---------------------------------------------------------------------------
// Kernel 1: q/k/v projections, fused.  C = X @ W  for 3 weight matrices.
// ---------------------------------------------------------------------------
__global__ __launch_bounds__(256) void qkv_kernel(
    const float* __restrict__ x,
    const float* __restrict__ Wq, const float* __restrict__ Wk,
    const float* __restrict__ Wv,
    float* __restrict__ qo, float* __restrict__ ko, float* __restrict__ vo)
{
    const int TM = 16;
    __shared__ float xs[TM][D_];
    const int r0 = blockIdx.x * TM;
    const int j  = threadIdx.x;

    for (int i = threadIdx.x; i < TM * D_ / 4; i += 256) {
        int r = i / (D_ / 4);
        int c = (i % (D_ / 4)) * 4;
        *(float4*)&xs[r][c] = *(const float4*)&x[(size_t)(r0 + r) * D_ + c];
    }
    __syncthreads();

    float aq[TM], ak[TM], av[TM];
#pragma unroll
    for (int r = 0; r < TM; ++r) { aq[r] = 0.f; ak[r] = 0.f; av[r] = 0.f; }

    for (int kk = 0; kk < D_; kk += 4) {
        float wq0 = Wq[(kk + 0) * D_ + j], wq1 = Wq[(kk + 1) * D_ + j];
        float wq2 = Wq[(kk + 2) * D_ + j], wq3 = Wq[(kk + 3) * D_ + j];
        float wk0 = Wk[(kk + 0) * D_ + j], wk1 = Wk[(kk + 1) * D_ + j];
        float wk2 = Wk[(kk + 2) * D_ + j], wk3 = Wk[(kk + 3) * D_ + j];
        float wv0 = Wv[(kk + 0) * D_ + j], wv1 = Wv[(kk + 1) * D_ + j];
        float wv2 = Wv[(kk + 2) * D_ + j], wv3 = Wv[(kk + 3) * D_ + j];
#pragma unroll
        for (int r = 0; r < TM; ++r) {
            float4 xv = *(const float4*)&xs[r][kk];
            aq[r] = fmaf(xv.x, wq0, aq[r]); aq[r] = fmaf(xv.y, wq1, aq[r]);
            aq[r] = fmaf(xv.z, wq2, aq[r]); aq[r] = fmaf(xv.w, wq3, aq[r]);
            ak[r] = fmaf(xv.x, wk0, ak[r]); ak[r] = fmaf(xv.y, wk1, ak[r]);
            ak[r] = fmaf(xv.z, wk2, ak[r]); ak[r] = fmaf(xv.w, wk3, ak[r]);
            av[r] = fmaf(xv.x, wv0, av[r]); av[r] = fmaf(xv.y, wv1, av[r]);
            av[r] = fmaf(xv.z, wv2, av[r]); av[r] = fmaf(xv.w, wv3, av[r]);
        }
    }
#pragma unroll
    for (int r = 0; r < TM; ++r) {
        qo[(size_t)(r0 + r) * D_ + j] = aq[r];
        ko[(size_t)(r0 + r) * D_ + j] = ak[r];
        vo[(size_t)(r0 + r) * D_ + j] = av[r];
    }
}

// ---------------------------------------------------------------------------
// Kernel 2: scores = qk^T/sqrt(32)+res, written to d_out; partial column
// softmax stats (max & sumexp over each 64-row tile) -> workspace.
// Grid: 256 g * 8 row-tiles.  Thread t = score column.
// ---------------------------------------------------------------------------
__global__ __launch_bounds__(512) void scores_kernel(
    const float* __restrict__ q, const float* __restrict__ k,
    const float* __restrict__ res, float* __restrict__ sc_out,
    float* __restrict__ pmax, float* __restrict__ psum)
{
    const int bid = blockIdx.x;
    const int g   = bid >> 3;         // (b,f,h) group
    const int st  = bid & 7;          // row tile
    const int bf  = g >> 3;
    const int h   = g & 7;
    const size_t rowbase = (size_t)bf * S_ * D_ + (size_t)h * DK_;
    const size_t sbase   = (size_t)g * S_ * S_;
    const int t  = threadIdx.x;
    const int s0 = st * 64;

    float kreg[DK_];
#pragma unroll
    for (int i = 0; i < DK_; i += 4) {
        float4 kv = *(const float4*)&k[rowbase + (size_t)t * D_ + i];
        kreg[i] = kv.x; kreg[i + 1] = kv.y; kreg[i + 2] = kv.z; kreg[i + 3] = kv.w;
    }

    const float scale = 0.17677669529663687f;  // 1/sqrt(32)
    float m = -1e30f, z = 0.f;
    for (int s = s0; s < s0 + 64; ++s) {
        float sc = 0.f;
#pragma unroll
        for (int i = 0; i < DK_; i += 4) {
            float4 qv = *(const float4*)&q[rowbase + (size_t)s * D_ + i];
            sc = fmaf(qv.x, kreg[i + 0], sc);
            sc = fmaf(qv.y, kreg[i + 1], sc);
            sc = fmaf(qv.z, kreg[i + 2], sc);
            sc = fmaf(qv.w, kreg[i + 3], sc);
        }
        sc = fmaf(sc, scale, res[sbase + (size_t)s * S_ + t]);
        sc_out[sbase + (size_t)s * S_ + t] = sc;
        float nm = fmaxf(m, sc);
        z = z * __expf(m - nm) + __expf(sc - nm);
        m = nm;
    }
    pmax[(size_t)bid * S_ + t] = m;
    psum[(size_t)bid * S_ + t] = z;
}

// ---------------------------------------------------------------------------
// Kernel 3: merge 8 partial stats per (g,t) -> global column max M, inv sum iZ
// ---------------------------------------------------------------------------
__global__ __launch_bounds__(256) void stats_kernel(
    const float* __restrict__ pmax, const float* __restrict__ psum,
    float* __restrict__ M, float* __restrict__ iZ)
{
    const int idx = blockIdx.x * 256 + threadIdx.x;   // g*512 + t
    const int g = idx >> 9;
    const int t = idx & 511;
    float m = -1e30f;
    float pm[8];
#pragma unroll
    for (int i = 0; i < 8; ++i) {
        pm[i] = pmax[((size_t)g * 8 + i) * S_ + t];
        m = fmaxf(m, pm[i]);
    }
    float z = 0.f;
#pragma unroll
    for (int i = 0; i < 8; ++i)
        z += psum[((size_t)g * 8 + i) * S_ + t] * __expf(pm[i] - m);
    M[idx]  = m;
    iZ[idx] = 1.f / z;
}

// ---------------------------------------------------------------------------
// Kernel 4: ctx[s,v] = sum_t exp(sc[s,t]-M[t])*iZ[t] * V[t,v]
// Grid: 256 g * 4 row-tiles (reversed for L3 locality of the scores re-read).
// Block 256 threads: thread = (rslot 0..31, vq 0..7); 4 rows x 4 v each.
// ---------------------------------------------------------------------------
__global__ __launch_bounds__(256) void pv_kernel(
    const float* __restrict__ sc, const float* __restrict__ v,
    const float* __restrict__ M, const float* __restrict__ iZ,
    float* __restrict__ ctx)
{
    const int idx = (int)gridDim.x - 1 - (int)blockIdx.x;  // reverse order
    const int g  = idx >> 2;
    const int rt = idx & 3;
    const int bf = g >> 3;
    const int h  = g & 7;
    const size_t sbase = (size_t)g * S_ * S_;
    const size_t vrow  = (size_t)bf * S_ * D_ + (size_t)h * DV_;
    const int s0 = rt * 128;

    __shared__ float Ml[S_];
    __shared__ float iZl[S_];
    __shared__ float e_lds[128][65];
    __shared__ float v_lds[64][32];

    for (int i = threadIdx.x; i < S_; i += 256) {
        Ml[i]  = M[(size_t)g * S_ + i];
        iZl[i] = iZ[(size_t)g * S_ + i];
    }

    const int rslot = threadIdx.x >> 3;   // 0..31
    const int vq    = threadIdx.x & 7;    // 0..7

    float acc[4][4];
#pragma unroll
    for (int r = 0; r < 4; ++r)
#pragma unroll
        for (int j = 0; j < 4; ++j) acc[r][j] = 0.f;

    for (int tc = 0; tc < S_; tc += 64) {
        __syncthreads();   // protects LDS reuse + initial Ml/iZl stage
        // stage exp-normalized scores chunk: 128 rows x 64 cols
        for (int i = threadIdx.x; i < 128 * 16; i += 256) {
            int r  = i >> 4;
            int c4 = (i & 15) * 4;
            float4 s4 = *(const float4*)&sc[sbase + (size_t)(s0 + r) * S_ + tc + c4];
            e_lds[r][c4 + 0] = __expf(s4.x - Ml[tc + c4 + 0]) * iZl[tc + c4 + 0];
            e_lds[r][c4 + 1] = __expf(s4.y - Ml[tc + c4 + 1]) * iZl[tc + c4 + 1];
            e_lds[r][c4 + 2] = __expf(s4.z - Ml[tc + c4 + 2]) * iZl[tc + c4 + 2];
            e_lds[r][c4 + 3] = __expf(s4.w - Ml[tc + c4 + 3]) * iZl[tc + c4 + 3];
        }
        // stage V chunk: 64 rows x 32 cols
        for (int i = threadIdx.x; i < 64 * 8; i += 256) {
            int r  = i >> 3;
            int c4 = (i & 7) * 4;
            *(float4*)&v_lds[r][c4] =
                *(const float4*)&v[vrow + (size_t)(tc + r) * D_ + c4];
        }
        __syncthreads();
        // register-tiled accumulate: 4 rows x 4 v per thread
        for (int tt = 0; tt < 64; tt += 4) {
            float4 vv0 = *(const float4*)&v_lds[tt + 0][vq * 4];
            float4 vv1 = *(const float4*)&v_lds[tt + 1][vq * 4];
            float4 vv2 = *(const float4*)&v_lds[tt + 2][vq * 4];
            float4 vv3 = *(const float4*)&v_lds[tt + 3][vq * 4];
#pragma unroll
            for (int rr = 0; rr < 4; ++rr) {
                float4 e4 = *(const float4*)&e_lds[rslot * 4 + rr][tt];
                acc[rr][0] = fmaf(e4.x, vv0.x, acc[rr][0]);
                acc[rr][1] = fmaf(e4.x, vv0.y, acc[rr][1]);
                acc[rr][2] = fmaf(e4.x, vv0.z, acc[rr][2]);
                acc[rr][3] = fmaf(e4.x, vv0.w, acc[rr][3]);
                acc[rr][0] = fmaf(e4.y, vv1.x, acc[rr][0]);
                acc[rr][1] = fmaf(e4.y, vv1.y, acc[rr][1]);
                acc[rr][2] = fmaf(e4.y, vv1.z, acc[rr][2]);
                acc[rr][3] = fmaf(e4.y, vv1.w, acc[rr][3]);
                acc[rr][0] = fmaf(e4.z, vv2.x, acc[rr][0]);
                acc[rr][1] = fmaf(e4.z, vv2.y, acc[rr][1]);
                acc[rr][2] = fmaf(e4.z, vv2.z, acc[rr][2]);
                acc[rr][3] = fmaf(e4.z, vv2.w, acc[rr][3]);
                acc[rr][0] = fmaf(e4.w, vv3.x, acc[rr][0]);
                acc[rr][1] = fmaf(e4.w, vv3.y, acc[rr][1]);
                acc[rr][2] = fmaf(e4.w, vv3.z, acc[rr][2]);
                acc[rr][3] = fmaf(e4.w, vv3.w, acc[rr][3]);
            }
        }
    }

#pragma unroll
    for (int rr = 0; rr < 4; ++rr) {
        float* crow = &ctx[((size_t)bf * S_ + s0 + rslot * 4 + rr) * D_
                           + (size_t)h * DV_ + vq * 4];
        float4 o;
        o.x = acc[rr][0]; o.y = acc[rr][1]; o.z = acc[rr][2]; o.w = acc[rr][3];
        *(float4*)crow = o;
    }
}

// ---------------------------------------------------------------------------
// Kernel 5: out = LayerNorm(ctx @ W_fc + x) * g + b
// ---------------------------------------------------------------------------
__global__ __launch_bounds__(256) void out_kernel(
    const float* __restrict__ ctx, const float* __restrict__ x,
    const float* __restrict__ Wfc, const float* __restrict__ gam,
    const float* __restrict__ bet, float* __restrict__ out)
{
    const int TM = 16;
    __shared__ float cs[TM][D_];
    __shared__ float red[TM][4][2];
    const int r0 = blockIdx.x * TM;
    const int j  = threadIdx.x;

    for (int i = threadIdx.x; i < TM * D_ / 4; i += 256) {
        int r = i / (D_ / 4);
        int c = (i % (D_ / 4)) * 4;
        *(float4*)&cs[r][c] = *(const float4*)&ctx[(size_t)(r0 + r) * D_ + c];
    }
    __syncthreads();

    float y[TM];
#pragma unroll
    for (int r = 0; r < TM; ++r) y[r] = 0.f;

    for (int kk = 0; kk < D_; kk += 4) {
        float w0 = Wfc[(kk + 0) * D_ + j], w1 = Wfc[(kk + 1) * D_ + j];
        float w2 = Wfc[(kk + 2) * D_ + j], w3 = Wfc[(kk + 3) * D_ + j];
#pragma unroll
        for (int r = 0; r < TM; ++r) {
            float4 c4 = *(const float4*)&cs[r][kk];
            y[r] = fmaf(c4.x, w0, y[r]); y[r] = fmaf(c4.y, w1, y[r]);
            y[r] = fmaf(c4.z, w2, y[r]); y[r] = fmaf(c4.w, w3, y[r]);
        }
    }
#pragma unroll
    for (int r = 0; r < TM; ++r) y[r] += x[(size_t)(r0 + r) * D_ + j];

    const int lane = threadIdx.x & 63;
    const int w    = threadIdx.x >> 6;
#pragma unroll
    for (int r = 0; r < TM; ++r) {
        float s1 = y[r], s2 = y[r] * y[r];
        for (int off = 32; off; off >>= 1) {
            s1 += __shfl_xor(s1, off);
            s2 += __shfl_xor(s2, off);
        }
        if (lane == 0) { red[r][w][0] = s1; red[r][w][1] = s2; }
    }
    __syncthreads();

#pragma unroll
    for (int r = 0; r < TM; ++r) {
        float s1 = red[r][0][0] + red[r][1][0] + red[r][2][0] + red[r][3][0];
        float s2 = red[r][0][1] + red[r][1][1] + red[r][2][1] + red[r][3][1];
        float mu  = s1 * (1.f / D_);
        float var = s2 * (1.f / D_) - mu * mu;
        float o = (y[r] - mu) * rsqrtf(var + LN_EPS) * gam[j] + bet[j];
        out[(size_t)(r0 + r) * D_ + j] = o;
    }
}

extern "C" void kernel_launch(void* const* d_in, const int* in_sizes, int n_in,
                              void* d_out, int out_size, void* d_ws, size_t ws_size,
                              hipStream_t stream)
{
    const float* x   = (const float*)d_in[0];
    const float* res = (const float*)d_in[1];
    const float* Wq  = (const float*)d_in[2];
    const float* Wk  = (const float*)d_in[3];
    const float* Wv  = (const float*)d_in[4];
    const float* Wfc = (const float*)d_in[5];
    const float* gam = (const float*)d_in[6];
    const float* bet = (const float*)d_in[7];

    float* out    = (float*)d_out;
    float* scores = out + (size_t)NROWS * D_;   // output 1 after output 0

    float* q    = (float*)d_ws;
    float* k    = q    + (size_t)NROWS * D_;
    float* v    = k    + (size_t)NROWS * D_;
    float* ctx  = v    + (size_t)NROWS * D_;
    float* pmax = ctx  + (size_t)NROWS * D_;
    float* psum = pmax + (size_t)NG * 8 * S_;
    float* M    = psum + (size_t)NG * 8 * S_;
    float* iZ   = M    + (size_t)NG * S_;

    qkv_kernel<<<dim3(NROWS / 16), 256, 0, stream>>>(x, Wq, Wk, Wv, q, k, v);
    scores_kernel<<<dim3(NG * 8), 512, 0, stream>>>(q, k, res, scores, pmax, psum);
    stats_kernel<<<dim3(NG * S_ / 256), 256, 0, stream>>>(pmax, psum, M, iZ);
    pv_kernel<<<dim3(NG * 4), 256, 0, stream>>>(scores, v, M, iZ, ctx);
    out_kernel<<<dim3(NROWS / 16), 256, 0, stream>>>(ctx, x, Wfc, gam, bet, out);
}